// Round 4
// baseline (244.075 us; speedup 1.0000x reference)
//
#include <hip/hip_runtime.h>
#include <stdint.h>

typedef __bf16 bf16x8 __attribute__((ext_vector_type(8)));
typedef float f32x4 __attribute__((ext_vector_type(4)));

#define EPS 1e-5f

#define WAITVM(N) asm volatile("s_waitcnt vmcnt(" #N ")" ::: "memory")
#define WAITLGKM0 asm volatile("s_waitcnt lgkmcnt(0)" ::: "memory")

__device__ __forceinline__ void gl16(const void* g, void* l) {
    __builtin_amdgcn_global_load_lds(
        (const __attribute__((address_space(1))) unsigned int*)g,
        (__attribute__((address_space(3))) unsigned int*)l, 16, 0, 0);
}

__device__ __forceinline__ float b2f(unsigned short u) {
    union { unsigned int i; float f; } c; c.i = ((unsigned int)u) << 16; return c.f;
}
__device__ __forceinline__ unsigned short f2b(float f) {
    union { float f; unsigned int i; } c; c.f = f;
    unsigned int i = c.i;
    return (unsigned short)((i + 0x7FFFu + ((i >> 16) & 1u)) >> 16);
}

__global__ void k_zero(float* __restrict__ p, int n) {
    int i = blockIdx.x * 256 + threadIdx.x;
    if (i < n) p[i] = 0.0f;
}

// Canonicalize params to bf16.
// wt1: [kb(64)][n(256)][8] (k-chunked for global_load_lds staging), B[n][k]=lw[k][n]
// rwb: plain [512][256]
// vec = {lb(256), g1(256), b1(256), rb(512), ga(512), ba(512)}
__global__ void k_params(const float* __restrict__ lw, const float* __restrict__ rw,
                         const float* __restrict__ lb, const float* __restrict__ g1,
                         const float* __restrict__ b1, const float* __restrict__ rb,
                         const float* __restrict__ ga, const float* __restrict__ ba,
                         unsigned short* __restrict__ wt1,
                         unsigned short* __restrict__ rwb,
                         unsigned short* __restrict__ vec) {
    int gid = blockIdx.x * 256 + threadIdx.x;
    if (gid < 131072) {
        int k = gid >> 8, n = gid & 255;
        wt1[((size_t)(k >> 3) * 256 + n) * 8 + (k & 7)] = f2b(lw[gid]);
    } else if (gid < 262144) {
        int j = gid - 131072;
        rwb[j] = f2b(rw[j]);
    } else if (gid < 264448) {
        int j = gid - 262144;
        if (j < 256)       vec[j] = f2b(lb[j]);
        else if (j < 512)  vec[j] = f2b(g1[j - 256]);
        else if (j < 768)  vec[j] = f2b(b1[j - 512]);
        else if (j < 1280) vec[j] = f2b(rb[j - 768]);
        else if (j < 1792) vec[j] = f2b(ga[j - 1280]);
        else               vec[j] = f2b(ba[j - 1792]);
    }
}

// per-row LN stats of x2 (row length 256); one wave per row
__global__ __launch_bounds__(256) void k_stats(const float* __restrict__ x2,
                                               float2* __restrict__ stats) {
    int t = threadIdx.x, lane = t & 63, w = t >> 6;
    size_t row = (size_t)blockIdx.x * 4 + w;
    float4 f = *(const float4*)(x2 + row * 256 + lane * 4);
    float s = f.x + f.y + f.z + f.w;
    float q = f.x * f.x + f.y * f.y + f.z * f.z + f.w * f.w;
#pragma unroll
    for (int msk = 1; msk < 64; msk <<= 1) {
        s += __shfl_xor(s, msk, 64);
        q += __shfl_xor(q, msk, 64);
    }
    float mn = s * (1.0f / 256.0f);
    float rstd = rsqrtf(q * (1.0f / 256.0f) - mn * mn + EPS);
    if (lane == 0) stats[row] = make_float2(mn, rstd);
}

// ctxraw[b,h,d,e] = sum_m q[d,m]*E[e,m], n2=LN(x2) on the fly.
// grid 512 = (b,h)(64) x chunk(8 of 512 tokens); 256 thr
__global__ __launch_bounds__(256) void k_ctx(const float* __restrict__ x2,
                                             const float2* __restrict__ stats,
                                             const unsigned short* __restrict__ vec,
                                             float* __restrict__ ctxraw) {
    __shared__ float E[64 * 36];
    __shared__ float Q[64 * 36];
    __shared__ float gs[32], bs[32];
    int bh = blockIdx.x >> 3;
    int b = bh >> 3, h = bh & 7;
    int ch = blockIdx.x & 7;
    int t = threadIdx.x;
    if (t < 32) { gs[t] = b2f(vec[256 + h * 32 + t]); bs[t] = b2f(vec[512 + h * 32 + t]); }
    __syncthreads();
    int d = t >> 3, e0 = (t & 7) * 4;
    float a0 = 0.f, a1 = 0.f, a2 = 0.f, a3 = 0.f;
    const float* base = x2 + ((size_t)b * 4096 + ch * 512) * 256 + h * 32;
    int srow = b * 4096 + ch * 512;
    const int m = t >> 2, c0 = (t & 3) * 8;
    for (int s0 = 0; s0 < 512; s0 += 64) {
        float2 st = stats[srow + s0 + m];
        const float4* p = (const float4*)(base + (size_t)(s0 + m) * 256 + c0);
        float4 f0 = p[0], f1 = p[1];
        float ev[8];
        ev[0] = __expf((f0.x - st.x) * st.y * gs[c0 + 0] + bs[c0 + 0]);
        ev[1] = __expf((f0.y - st.x) * st.y * gs[c0 + 1] + bs[c0 + 1]);
        ev[2] = __expf((f0.z - st.x) * st.y * gs[c0 + 2] + bs[c0 + 2]);
        ev[3] = __expf((f0.w - st.x) * st.y * gs[c0 + 3] + bs[c0 + 3]);
        ev[4] = __expf((f1.x - st.x) * st.y * gs[c0 + 4] + bs[c0 + 4]);
        ev[5] = __expf((f1.y - st.x) * st.y * gs[c0 + 5] + bs[c0 + 5]);
        ev[6] = __expf((f1.z - st.x) * st.y * gs[c0 + 6] + bs[c0 + 6]);
        ev[7] = __expf((f1.w - st.x) * st.y * gs[c0 + 7] + bs[c0 + 7]);
        float ps = ev[0] + ev[1] + ev[2] + ev[3] + ev[4] + ev[5] + ev[6] + ev[7];
        ps += __shfl_xor(ps, 1, 64);
        ps += __shfl_xor(ps, 2, 64);
        float qi = 1.0f / ps;
        *(float4*)(E + m * 36 + c0)     = make_float4(ev[0], ev[1], ev[2], ev[3]);
        *(float4*)(E + m * 36 + c0 + 4) = make_float4(ev[4], ev[5], ev[6], ev[7]);
        *(float4*)(Q + m * 36 + c0)     = make_float4(ev[0]*qi, ev[1]*qi, ev[2]*qi, ev[3]*qi);
        *(float4*)(Q + m * 36 + c0 + 4) = make_float4(ev[4]*qi, ev[5]*qi, ev[6]*qi, ev[7]*qi);
        __syncthreads();
#pragma unroll 4
        for (int mm = 0; mm < 64; mm++) {
            float qd = Q[mm * 36 + d];
            float4 e4 = *(const float4*)(E + mm * 36 + e0);
            a0 += qd * e4.x; a1 += qd * e4.y; a2 += qd * e4.z; a3 += qd * e4.w;
        }
        __syncthreads();
    }
    float* dst = ctxraw + ((size_t)bh << 10) + (d << 5) + e0;
    atomicAdd(dst + 0, a0);
    atomicAdd(dst + 1, a1);
    atomicAdd(dst + 2, a2);
    atomicAdd(dst + 3, a3);
}

// w2t layout: w2g[b][kb(32)][o(512)][8] bf16, value = (1/colsum[c]) * sum_d ctx[d,c]*rw[o, h*32+d]
// where c = h*32+e (the gemm2 k-dim), kb = c>>3.
__global__ __launch_bounds__(256) void k_w2(const float* __restrict__ ctxraw,
                                            const unsigned short* __restrict__ rwb,
                                            unsigned short* __restrict__ w2t) {
    __shared__ float ctx_s[1024];   // [d][e]
    __shared__ float cinv[32];
    int blk = blockIdx.x;
    int b = blk >> 6, h = (blk >> 3) & 7, os = blk & 7;
    int bh = b * 8 + h;
    int t = threadIdx.x;
#pragma unroll
    for (int i = 0; i < 4; i++) ctx_s[t + 256 * i] = ctxraw[((size_t)bh << 10) + t + 256 * i];
    __syncthreads();
    if (t < 32) {
        float s = 0.f;
#pragma unroll
        for (int d = 0; d < 32; d++) s += ctx_s[d * 32 + t];
        cinv[t] = 1.0f / s;
    }
    __syncthreads();
    int o = os * 64 + (t >> 2);
    int e0 = (t & 3) * 8;
    float wv[32];
    const uint4* wp = (const uint4*)(rwb + (size_t)o * 256 + h * 32);
#pragma unroll
    for (int qd = 0; qd < 4; qd++) {
        uint4 u = wp[qd];
        unsigned int uu[4] = {u.x, u.y, u.z, u.w};
#pragma unroll
        for (int j = 0; j < 4; j++) {
            wv[qd * 8 + j * 2]     = b2f((unsigned short)(uu[j] & 0xFFFFu));
            wv[qd * 8 + j * 2 + 1] = b2f((unsigned short)(uu[j] >> 16));
        }
    }
    float s[8];
#pragma unroll
    for (int j = 0; j < 8; j++) s[j] = 0.f;
#pragma unroll 8
    for (int d = 0; d < 32; d++) {
        float w = wv[d];
#pragma unroll
        for (int j = 0; j < 8; j++) s[j] += ctx_s[d * 32 + e0 + j] * w;
    }
    ushort4 o4a, o4b;
    o4a.x = f2b(s[0] * cinv[e0 + 0]); o4a.y = f2b(s[1] * cinv[e0 + 1]);
    o4a.z = f2b(s[2] * cinv[e0 + 2]); o4a.w = f2b(s[3] * cinv[e0 + 3]);
    o4b.x = f2b(s[4] * cinv[e0 + 4]); o4b.y = f2b(s[5] * cinv[e0 + 5]);
    o4b.z = f2b(s[6] * cinv[e0 + 6]); o4b.w = f2b(s[7] * cinv[e0 + 7]);
    int kb = h * 4 + (e0 >> 3);
    unsigned short* dst = w2t + (size_t)b * 131072 + ((size_t)kb * 512 + o) * 8;
    *(ushort4*)dst = o4a;
    *(ushort4*)(dst + 4) = o4b;
}

// Fused GEMM1+LN+GEMM2+LN+residual.  grid 512, 256 thr / 4 waves, 64 rows/block,
// 2 blocks/CU (dyn LDS 66560 B + 1 KB static, __launch_bounds__(256,2)).
// Phase 1 (K=512, BK=32, dbuf, counted vmcnt -- r2-proven shape):
//   n1 = LN(x1 @ W1 + lb) -> LDS [64][264] bf16.  waves row-split (16 rows each).
// Phase 2 (K=256): out = LN(n1 @ w2t^T + rb)*ga + ba + x1.
//   B read DIRECTLY global->register (w2t is L2-resident) -- no LDS staging,
//   no barriers in the P2 loop.  waves: (wr=w>>1) rows 32, (wc=w&1) cols 256.
// Epilogues use __syncthreads() only.  rep f32 [64][260] aliases whole pool.
__global__ __launch_bounds__(256, 2) void k_fused(
    const float* __restrict__ x1, const unsigned short* __restrict__ wt1,
    const unsigned short* __restrict__ w2t, const unsigned short* __restrict__ vec,
    float* __restrict__ out) {
    extern __shared__ __align__(16) char pool[];
    unsigned short* n1s = (unsigned short*)pool;          // [64][264]
    char* Breg = pool + 33792;                            // 32 KB P1 dbuf
    __shared__ float2 red[64][2];

    const int t = threadIdx.x;
    const int lane = t & 63, w = t >> 6;
    const int l15 = lane & 15, quad = lane >> 4;
    const int wr = w >> 1, wc = w & 1;
    const int rb = blockIdx.x;
    const int row0 = rb << 6;
    const char* wt1c = (const char*)wt1;
    const char* wbase = (const char*)w2t + (size_t)(rb >> 6) * 262144;

    // ---- Phase 1: rows w*16+l15, K=512, 16 steps, B dbuf ----
    const float* xrow = x1 + (size_t)(row0 + (w << 4) + l15) * 512 + quad * 8;

    f32x4 acc[16];
#pragma unroll
    for (int i = 0; i < 16; i++) acc[i] = (f32x4){0.f, 0.f, 0.f, 0.f};

#pragma unroll
    for (int i = 0; i < 4; i++)
        gl16(wt1c + i * 4096 + t * 16, Breg + i * 4096 + t * 16);
    float4 fa[2][2];
    fa[0][0] = *(const float4*)xrow;
    fa[0][1] = *(const float4*)(xrow + 4);

#pragma unroll
    for (int s = 0; s < 16; ++s) {
        const int cur = s & 1;
        if (s < 15) {
            const float* xn = xrow + (s + 1) * 32;
            fa[cur ^ 1][0] = *(const float4*)xn;
            fa[cur ^ 1][1] = *(const float4*)(xn + 4);
#pragma unroll
            for (int i = 0; i < 4; i++)
                gl16(wt1c + (size_t)(s + 1) * 16384 + i * 4096 + t * 16,
                     Breg + (cur ^ 1) * 16384 + i * 4096 + t * 16);
        }
        bf16x8 af;
        af[0] = (__bf16)fa[cur][0].x; af[1] = (__bf16)fa[cur][0].y;
        af[2] = (__bf16)fa[cur][0].z; af[3] = (__bf16)fa[cur][0].w;
        af[4] = (__bf16)fa[cur][1].x; af[5] = (__bf16)fa[cur][1].y;
        af[6] = (__bf16)fa[cur][1].z; af[7] = (__bf16)fa[cur][1].w;
        if (s < 15) { WAITVM(6); } else { WAITVM(0); }
        __builtin_amdgcn_s_barrier();
        const char* Bc = Breg + cur * 16384 + quad * 4096 + l15 * 16;
#pragma unroll
        for (int nb = 0; nb < 16; nb++) {
            bf16x8 bf = *(const bf16x8*)(Bc + nb * 256);
            acc[nb] = __builtin_amdgcn_mfma_f32_16x16x32_bf16(af, bf, acc[nb], 0, 0, 0);
        }
        WAITLGKM0;
        __builtin_amdgcn_s_barrier();
    }

    // ---- Phase 1 epilogue: bias + LN(256) (in-wave) -> n1s ----
    float bc_[16], gg_[16], bb_[16];
#pragma unroll
    for (int nb = 0; nb < 16; nb++) {
        int col = (nb << 4) + l15;
        bc_[nb] = b2f(vec[col]);
        gg_[nb] = b2f(vec[256 + col]);
        bb_[nb] = b2f(vec[512 + col]);
    }
#pragma unroll
    for (int nb = 0; nb < 16; nb++) {
#pragma unroll
        for (int r = 0; r < 4; r++) acc[nb][r] += bc_[nb];
    }
    float mean_[4], rstd_[4];
#pragma unroll
    for (int r = 0; r < 4; r++) {
        float s = 0.f, q = 0.f;
#pragma unroll
        for (int nb = 0; nb < 16; nb++) { float v = acc[nb][r]; s += v; q += v * v; }
#pragma unroll
        for (int msk = 1; msk < 16; msk <<= 1) {
            s += __shfl_xor(s, msk, 64);
            q += __shfl_xor(q, msk, 64);
        }
        float mn = s * (1.0f / 256.0f);
        mean_[r] = mn;
        rstd_[r] = rsqrtf(q * (1.0f / 256.0f) - mn * mn + EPS);
    }
#pragma unroll
    for (int nb = 0; nb < 16; nb++) {
        int col = (nb << 4) + l15;
#pragma unroll
        for (int r = 0; r < 4; r++) {
            int rr = (w << 4) + (quad << 2) + r;
            n1s[rr * 264 + col] =
                f2b((acc[nb][r] - mean_[r]) * rstd_[r] * gg_[nb] + bb_[nb]);
        }
    }
    __syncthreads();   // n1s complete; full drain (no live prefetch to preserve)

    // ---- Phase 2: wave (wr,wc): rows wr*32..+32, cols wc*256..+256 ----
    // B fragments loaded directly from global (w2t L2-resident); no barriers.
    f32x4 acc2[2][16];
#pragma unroll
    for (int m = 0; m < 2; m++)
#pragma unroll
        for (int nb = 0; nb < 16; nb++) acc2[m][nb] = (f32x4){0.f, 0.f, 0.f, 0.f};
    const unsigned short* an0 = n1s + ((wr << 5) + l15) * 264 + quad * 8;
    const char* bq = wbase + quad * 8192 + ((wc << 8) + l15) * 16;

    for (int s = 0; s < 8; ++s) {
        bf16x8 a0 = *(const bf16x8*)(an0 + s * 32);
        bf16x8 a1 = *(const bf16x8*)(an0 + 16 * 264 + s * 32);
        const char* bs8 = bq + (size_t)s * 32768;
#pragma unroll
        for (int nb = 0; nb < 16; nb++) {
            bf16x8 bf = *(const bf16x8*)(bs8 + nb * 256);
            acc2[0][nb] = __builtin_amdgcn_mfma_f32_16x16x32_bf16(a0, bf, acc2[0][nb], 0, 0, 0);
            acc2[1][nb] = __builtin_amdgcn_mfma_f32_16x16x32_bf16(a1, bf, acc2[1][nb], 0, 0, 0);
        }
    }

    // ---- Phase 2 epilogue: + rb, LN(512) cross-wave, residual, store ----
    float rb_[16], ga_[16], ba_[16];
#pragma unroll
    for (int nb = 0; nb < 16; nb++) {
        int col = (wc << 8) + (nb << 4) + l15;
        rb_[nb] = b2f(vec[768 + col]);
        ga_[nb] = b2f(vec[1280 + col]);
        ba_[nb] = b2f(vec[1792 + col]);
    }
#pragma unroll
    for (int m = 0; m < 2; m++)
#pragma unroll
        for (int nb = 0; nb < 16; nb++)
#pragma unroll
            for (int r = 0; r < 4; r++) acc2[m][nb][r] += rb_[nb];

#pragma unroll
    for (int m = 0; m < 2; m++)
#pragma unroll
        for (int r = 0; r < 4; r++) {
            float s = 0.f, q = 0.f;
#pragma unroll
            for (int nb = 0; nb < 16; nb++) { float v = acc2[m][nb][r]; s += v; q += v * v; }
#pragma unroll
            for (int msk = 1; msk < 16; msk <<= 1) {
                s += __shfl_xor(s, msk, 64);
                q += __shfl_xor(q, msk, 64);
            }
            if (l15 == 0)
                red[(wr << 5) + (m << 4) + (quad << 2) + r][wc] = make_float2(s, q);
        }
    __syncthreads();   // red complete AND all waves done reading n1s (pool free)
    float mean2[2][4], rstd2[2][4];
#pragma unroll
    for (int m = 0; m < 2; m++)
#pragma unroll
        for (int r = 0; r < 4; r++) {
            int rr = (wr << 5) + (m << 4) + (quad << 2) + r;
            float2 cA = red[rr][0], cB = red[rr][1];
            float s = cA.x + cB.x, q = cA.y + cB.y;
            float mn = s * (1.0f / 512.0f);
            mean2[m][r] = mn;
            rstd2[m][r] = rsqrtf(q * (1.0f / 512.0f) - mn * mn + EPS);
        }
    float* rep = (float*)pool;   // [64][260] f32, aliases n1s+Breg (both dead)
#pragma unroll
    for (int hv = 0; hv < 2; ++hv) {
        if (hv) __syncthreads();   // hv0 reads done before hv1 writes
        if (wc == hv) {
#pragma unroll
            for (int m = 0; m < 2; m++)
#pragma unroll
                for (int nb = 0; nb < 16; nb++) {
                    int col = (nb << 4) + l15;
                    int rl = (wr << 5) + (m << 4) + (quad << 2);
#pragma unroll
                    for (int r = 0; r < 4; r++)
                        rep[(rl + r) * 260 + col] =
                            (acc2[m][nb][r] - mean2[m][r]) * rstd2[m][r] * ga_[nb] + ba_[nb];
                }
        }
        __syncthreads();
#pragma unroll
        for (int rg = 0; rg < 4; rg++) {
            int row = (rg << 4) + (t >> 4);
#pragma unroll
            for (int j = 0; j < 4; j++) {
                int col = ((t & 15) << 2) + (j << 6);
                float4 v = *(const float4*)(rep + row * 260 + col);
                size_t g = (size_t)(row0 + row) * 512 + (hv << 8) + col;
                float4 xa = *(const float4*)(x1 + g);
                v.x += xa.x; v.y += xa.y; v.z += xa.z; v.w += xa.w;
                *(float4*)(out + g) = v;
            }
        }
    }
}

extern "C" void kernel_launch(void* const* d_in, const int* in_sizes, int n_in,
                              void* d_out, int out_size, void* d_ws, size_t ws_size,
                              hipStream_t stream) {
    const float* x1 = (const float*)d_in[0];
    const float* x2 = (const float*)d_in[1];
    const float* lw = (const float*)d_in[2];
    const float* lb = (const float*)d_in[3];
    const float* g1 = (const float*)d_in[4];
    const float* b1 = (const float*)d_in[5];
    const float* rw = (const float*)d_in[6];
    const float* rb = (const float*)d_in[7];
    const float* ga = (const float*)d_in[8];
    const float* ba = (const float*)d_in[9];
    float* out = (float*)d_out;

    char* ws = (char*)d_ws;
    float*          ctxr  = (float*)(ws);                       // 256 KB
    float2*         stats = (float2*)(ws + 262144);             // 256 KB
    unsigned short* wt1   = (unsigned short*)(ws + 524288);     // 256 KB
    unsigned short* rwb   = (unsigned short*)(ws + 786432);     // 256 KB
    unsigned short* vec   = (unsigned short*)(ws + 1048576);    // 4.5 KB
    unsigned short* w2t   = (unsigned short*)(ws + 1064960);    // 2 MB

    static bool attr_set = false;
    if (!attr_set) {
        hipFuncSetAttribute((const void*)k_fused,
                            hipFuncAttributeMaxDynamicSharedMemorySize, 66560);
        attr_set = true;
    }

    k_zero<<<dim3(256), dim3(256), 0, stream>>>(ctxr, 65536);
    k_params<<<dim3(1033), dim3(256), 0, stream>>>(lw, rw, lb, g1, b1, rb, ga, ba,
                                                   wt1, rwb, vec);
    k_stats<<<dim3(8192), dim3(256), 0, stream>>>(x2, stats);
    k_ctx<<<dim3(512), dim3(256), 0, stream>>>(x2, stats, vec, ctxr);
    k_w2<<<dim3(512), dim3(256), 0, stream>>>(ctxr, rwb, w2t);
    k_fused<<<dim3(512), dim3(256), 66560, stream>>>(x1, wt1, w2t, vec, out);
}

// Round 5
// 226.109 us; speedup vs baseline: 1.0795x; 1.0795x over previous
//
#include <hip/hip_runtime.h>
#include <stdint.h>

typedef __bf16 bf16x8 __attribute__((ext_vector_type(8)));
typedef float f32x4 __attribute__((ext_vector_type(4)));

#define EPS 1e-5f

#define WAITVM(N) asm volatile("s_waitcnt vmcnt(" #N ")" ::: "memory")
#define WAITLGKM0 asm volatile("s_waitcnt lgkmcnt(0)" ::: "memory")

__device__ __forceinline__ void gl16(const void* g, void* l) {
    __builtin_amdgcn_global_load_lds(
        (const __attribute__((address_space(1))) unsigned int*)g,
        (__attribute__((address_space(3))) unsigned int*)l, 16, 0, 0);
}

__device__ __forceinline__ float b2f(unsigned short u) {
    union { unsigned int i; float f; } c; c.i = ((unsigned int)u) << 16; return c.f;
}
__device__ __forceinline__ unsigned short f2b(float f) {
    union { float f; unsigned int i; } c; c.f = f;
    unsigned int i = c.i;
    return (unsigned short)((i + 0x7FFFu + ((i >> 16) & 1u)) >> 16);
}

// Canonicalize params to bf16 AND zero ctxraw (merged k_zero).
// wt1: [kb(64)][n(256)][8] (k-chunked for global_load_lds staging), B[n][k]=lw[k][n]
// rwb: plain [512][256]
// vec = {lb(256), g1(256), b1(256), rb(512), ga(512), ba(512)}
// tail: ctxraw[0..65536) = 0
__global__ void k_params(const float* __restrict__ lw, const float* __restrict__ rw,
                         const float* __restrict__ lb, const float* __restrict__ g1,
                         const float* __restrict__ b1, const float* __restrict__ rb,
                         const float* __restrict__ ga, const float* __restrict__ ba,
                         unsigned short* __restrict__ wt1,
                         unsigned short* __restrict__ rwb,
                         unsigned short* __restrict__ vec,
                         float* __restrict__ ctxr) {
    int gid = blockIdx.x * 256 + threadIdx.x;
    if (gid < 131072) {
        int k = gid >> 8, n = gid & 255;
        wt1[((size_t)(k >> 3) * 256 + n) * 8 + (k & 7)] = f2b(lw[gid]);
    } else if (gid < 262144) {
        int j = gid - 131072;
        rwb[j] = f2b(rw[j]);
    } else if (gid < 264448) {
        int j = gid - 262144;
        if (j < 256)       vec[j] = f2b(lb[j]);
        else if (j < 512)  vec[j] = f2b(g1[j - 256]);
        else if (j < 768)  vec[j] = f2b(b1[j - 512]);
        else if (j < 1280) vec[j] = f2b(rb[j - 768]);
        else if (j < 1792) vec[j] = f2b(ga[j - 1280]);
        else               vec[j] = f2b(ba[j - 1792]);
    } else if (gid < 329984) {
        ctxr[gid - 264448] = 0.0f;
    }
}

// per-row LN stats of x2 (row length 256); one wave per row
__global__ __launch_bounds__(256) void k_stats(const float* __restrict__ x2,
                                               float2* __restrict__ stats) {
    int t = threadIdx.x, lane = t & 63, w = t >> 6;
    size_t row = (size_t)blockIdx.x * 4 + w;
    float4 f = *(const float4*)(x2 + row * 256 + lane * 4);
    float s = f.x + f.y + f.z + f.w;
    float q = f.x * f.x + f.y * f.y + f.z * f.z + f.w * f.w;
#pragma unroll
    for (int msk = 1; msk < 64; msk <<= 1) {
        s += __shfl_xor(s, msk, 64);
        q += __shfl_xor(q, msk, 64);
    }
    float mn = s * (1.0f / 256.0f);
    float rstd = rsqrtf(q * (1.0f / 256.0f) - mn * mn + EPS);
    if (lane == 0) stats[row] = make_float2(mn, rstd);
}

// ctxraw[b,h,d,e] = sum_m q[d,m]*E[e,m], n2=LN(x2) on the fly.
// grid 1024 = (b,h)(64) x chunk(16 of 256 tokens); 256 thr; 4 blocks/CU
__global__ __launch_bounds__(256) void k_ctx(const float* __restrict__ x2,
                                             const float2* __restrict__ stats,
                                             const unsigned short* __restrict__ vec,
                                             float* __restrict__ ctxraw) {
    __shared__ float E[64 * 36];
    __shared__ float Q[64 * 36];
    __shared__ float gs[32], bs[32];
    int bh = blockIdx.x >> 4;
    int b = bh >> 3, h = bh & 7;
    int ch = blockIdx.x & 15;
    int t = threadIdx.x;
    if (t < 32) { gs[t] = b2f(vec[256 + h * 32 + t]); bs[t] = b2f(vec[512 + h * 32 + t]); }
    __syncthreads();
    int d = t >> 3, e0 = (t & 7) * 4;
    float a0 = 0.f, a1 = 0.f, a2 = 0.f, a3 = 0.f;
    const float* base = x2 + ((size_t)b * 4096 + ch * 256) * 256 + h * 32;
    int srow = b * 4096 + ch * 256;
    const int m = t >> 2, c0 = (t & 3) * 8;
    for (int s0 = 0; s0 < 256; s0 += 64) {
        float2 st = stats[srow + s0 + m];
        const float4* p = (const float4*)(base + (size_t)(s0 + m) * 256 + c0);
        float4 f0 = p[0], f1 = p[1];
        float ev[8];
        ev[0] = __expf((f0.x - st.x) * st.y * gs[c0 + 0] + bs[c0 + 0]);
        ev[1] = __expf((f0.y - st.x) * st.y * gs[c0 + 1] + bs[c0 + 1]);
        ev[2] = __expf((f0.z - st.x) * st.y * gs[c0 + 2] + bs[c0 + 2]);
        ev[3] = __expf((f0.w - st.x) * st.y * gs[c0 + 3] + bs[c0 + 3]);
        ev[4] = __expf((f1.x - st.x) * st.y * gs[c0 + 4] + bs[c0 + 4]);
        ev[5] = __expf((f1.y - st.x) * st.y * gs[c0 + 5] + bs[c0 + 5]);
        ev[6] = __expf((f1.z - st.x) * st.y * gs[c0 + 6] + bs[c0 + 6]);
        ev[7] = __expf((f1.w - st.x) * st.y * gs[c0 + 7] + bs[c0 + 7]);
        float ps = ev[0] + ev[1] + ev[2] + ev[3] + ev[4] + ev[5] + ev[6] + ev[7];
        ps += __shfl_xor(ps, 1, 64);
        ps += __shfl_xor(ps, 2, 64);
        float qi = 1.0f / ps;
        *(float4*)(E + m * 36 + c0)     = make_float4(ev[0], ev[1], ev[2], ev[3]);
        *(float4*)(E + m * 36 + c0 + 4) = make_float4(ev[4], ev[5], ev[6], ev[7]);
        *(float4*)(Q + m * 36 + c0)     = make_float4(ev[0]*qi, ev[1]*qi, ev[2]*qi, ev[3]*qi);
        *(float4*)(Q + m * 36 + c0 + 4) = make_float4(ev[4]*qi, ev[5]*qi, ev[6]*qi, ev[7]*qi);
        __syncthreads();
#pragma unroll 4
        for (int mm = 0; mm < 64; mm++) {
            float qd = Q[mm * 36 + d];
            float4 e4 = *(const float4*)(E + mm * 36 + e0);
            a0 += qd * e4.x; a1 += qd * e4.y; a2 += qd * e4.z; a3 += qd * e4.w;
        }
        __syncthreads();
    }
    float* dst = ctxraw + ((size_t)bh << 10) + (d << 5) + e0;
    atomicAdd(dst + 0, a0);
    atomicAdd(dst + 1, a1);
    atomicAdd(dst + 2, a2);
    atomicAdd(dst + 3, a3);
}

// w2t layout: w2g[b][kb(32)][o(512)][8] bf16, value = (1/colsum[c]) * sum_d ctx[d,c]*rw[o, h*32+d]
// where c = h*32+e (the gemm2 k-dim), kb = c>>3.
__global__ __launch_bounds__(256) void k_w2(const float* __restrict__ ctxraw,
                                            const unsigned short* __restrict__ rwb,
                                            unsigned short* __restrict__ w2t) {
    __shared__ float ctx_s[1024];   // [d][e]
    __shared__ float cinv[32];
    int blk = blockIdx.x;
    int b = blk >> 6, h = (blk >> 3) & 7, os = blk & 7;
    int bh = b * 8 + h;
    int t = threadIdx.x;
#pragma unroll
    for (int i = 0; i < 4; i++) ctx_s[t + 256 * i] = ctxraw[((size_t)bh << 10) + t + 256 * i];
    __syncthreads();
    if (t < 32) {
        float s = 0.f;
#pragma unroll
        for (int d = 0; d < 32; d++) s += ctx_s[d * 32 + t];
        cinv[t] = 1.0f / s;
    }
    __syncthreads();
    int o = os * 64 + (t >> 2);
    int e0 = (t & 3) * 8;
    float wv[32];
    const uint4* wp = (const uint4*)(rwb + (size_t)o * 256 + h * 32);
#pragma unroll
    for (int qd = 0; qd < 4; qd++) {
        uint4 u = wp[qd];
        unsigned int uu[4] = {u.x, u.y, u.z, u.w};
#pragma unroll
        for (int j = 0; j < 4; j++) {
            wv[qd * 8 + j * 2]     = b2f((unsigned short)(uu[j] & 0xFFFFu));
            wv[qd * 8 + j * 2 + 1] = b2f((unsigned short)(uu[j] >> 16));
        }
    }
    float s[8];
#pragma unroll
    for (int j = 0; j < 8; j++) s[j] = 0.f;
#pragma unroll 8
    for (int d = 0; d < 32; d++) {
        float w = wv[d];
#pragma unroll
        for (int j = 0; j < 8; j++) s[j] += ctx_s[d * 32 + e0 + j] * w;
    }
    ushort4 o4a, o4b;
    o4a.x = f2b(s[0] * cinv[e0 + 0]); o4a.y = f2b(s[1] * cinv[e0 + 1]);
    o4a.z = f2b(s[2] * cinv[e0 + 2]); o4a.w = f2b(s[3] * cinv[e0 + 3]);
    o4b.x = f2b(s[4] * cinv[e0 + 4]); o4b.y = f2b(s[5] * cinv[e0 + 5]);
    o4b.z = f2b(s[6] * cinv[e0 + 6]); o4b.w = f2b(s[7] * cinv[e0 + 7]);
    int kb = h * 4 + (e0 >> 3);
    unsigned short* dst = w2t + (size_t)b * 131072 + ((size_t)kb * 512 + o) * 8;
    *(ushort4*)dst = o4a;
    *(ushort4*)(dst + 4) = o4b;
}

// Fused GEMM1+LN+GEMM2+LN+residual (r2-proven version).
// grid 256 (1 block/CU), 512 thr / 8 waves, 128 rows per block.
// Phase 1: n1 = LN(x1 @ W1 + lb) -> LDS tile [128][264] bf16 (no HBM round-trip).
// Phase 2: out = LN(n1 @ w2t^T + rb)*ga + ba + x1.
// LDS pool (dynamic, 133120 B): [n1s 67584][B region 65536]
//   P1 B dbuf: Breg+0 / Breg+16384 (16 KB each)
//   P2 B dbuf: Breg+32768 (even s) / Breg+0 (odd s)
//   epilogue rep aliases pool as f32 [64][516]
__global__ __launch_bounds__(512, 1) void k_fused(
    const float* __restrict__ x1, const unsigned short* __restrict__ wt1,
    const unsigned short* __restrict__ w2t, const unsigned short* __restrict__ vec,
    float* __restrict__ out) {
    extern __shared__ __align__(16) char pool[];
    unsigned short* n1s = (unsigned short*)pool;          // [128][264]
    char* Breg = pool + 67584;

    const int t = threadIdx.x;
    const int lane = t & 63, w = t >> 6;
    const int l15 = lane & 15, quad = lane >> 4;
    const int rb = blockIdx.x;
    const int row0 = rb << 7;
    const char* wt1c = (const char*)wt1;
    const char* wbase = (const char*)w2t + (size_t)(rb >> 5) * 262144;

    const float* xrow = x1 + (size_t)(row0 + (w << 4) + l15) * 512 + quad * 8;

    f32x4 acc[16];
#pragma unroll
    for (int i = 0; i < 16; i++) acc[i] = (f32x4){0.f, 0.f, 0.f, 0.f};

    // prologue: stage P1 step0 + load A step0
#pragma unroll
    for (int i = 0; i < 2; i++)
        gl16(wt1c + ((w * 2 + i) << 10) + lane * 16,
             Breg + ((w * 2 + i) << 10) + lane * 16);
    float4 fa[2][2];
    fa[0][0] = *(const float4*)xrow;
    fa[0][1] = *(const float4*)(xrow + 4);

    // ---- Phase 1: K=512, 16 steps ----
#pragma unroll
    for (int s = 0; s < 16; ++s) {
        const int cur = s & 1;
        if (s < 15) {
            const float* xn = xrow + (s + 1) * 32;
            fa[cur ^ 1][0] = *(const float4*)xn;
            fa[cur ^ 1][1] = *(const float4*)(xn + 4);
#pragma unroll
            for (int i = 0; i < 2; i++)
                gl16(wt1c + (size_t)(s + 1) * 16384 + ((w * 2 + i) << 10) + lane * 16,
                     Breg + (cur ^ 1) * 16384 + ((w * 2 + i) << 10) + lane * 16);
        }
        bf16x8 af;
        af[0] = (__bf16)fa[cur][0].x; af[1] = (__bf16)fa[cur][0].y;
        af[2] = (__bf16)fa[cur][0].z; af[3] = (__bf16)fa[cur][0].w;
        af[4] = (__bf16)fa[cur][1].x; af[5] = (__bf16)fa[cur][1].y;
        af[6] = (__bf16)fa[cur][1].z; af[7] = (__bf16)fa[cur][1].w;
        if (s < 15) { WAITVM(4); } else { WAITVM(0); }
        __builtin_amdgcn_s_barrier();
        const char* Bc = Breg + cur * 16384 + quad * 4096 + l15 * 16;
#pragma unroll
        for (int cb = 0; cb < 16; cb++) {
            bf16x8 bf = *(const bf16x8*)(Bc + cb * 256);
            acc[cb] = __builtin_amdgcn_mfma_f32_16x16x32_bf16(af, bf, acc[cb], 0, 0, 0);
        }
        WAITLGKM0;
        __builtin_amdgcn_s_barrier();
    }

    // ---- Phase 1 epilogue: bias + LN(256) -> n1s ----
    // Load epilogue params FIRST (their vmcnt waits happen before the P2 prefetch
    // is issued, so in-order vmcnt retirement doesn't drain the prefetch).
    float bc_[16], gg_[16], bb_[16];
#pragma unroll
    for (int cb = 0; cb < 16; cb++) {
        int col = (cb << 4) + l15;
        bc_[cb] = b2f(vec[col]);
        gg_[cb] = b2f(vec[256 + col]);
        bb_[cb] = b2f(vec[512 + col]);
    }
    // issue P2 step0 prefetch (into Breg+32768, disjoint from P1 dbuf)
#pragma unroll
    for (int i = 0; i < 4; i++)
        gl16(wbase + ((w * 4 + i) << 10) + lane * 16,
             Breg + 32768 + ((w * 4 + i) << 10) + lane * 16);

#pragma unroll
    for (int cb = 0; cb < 16; cb++) {
#pragma unroll
        for (int r = 0; r < 4; r++) acc[cb][r] += bc_[cb];
    }
    float mean_[4], rstd_[4];
#pragma unroll
    for (int r = 0; r < 4; r++) {
        float s = 0.f, q = 0.f;
#pragma unroll
        for (int cb = 0; cb < 16; cb++) { float v = acc[cb][r]; s += v; q += v * v; }
#pragma unroll
        for (int msk = 1; msk < 16; msk <<= 1) {
            s += __shfl_xor(s, msk, 64);
            q += __shfl_xor(q, msk, 64);
        }
        float mn = s * (1.0f / 256.0f);
        mean_[r] = mn;
        rstd_[r] = rsqrtf(q * (1.0f / 256.0f) - mn * mn + EPS);
    }
#pragma unroll
    for (int cb = 0; cb < 16; cb++) {
        int col = (cb << 4) + l15;
#pragma unroll
        for (int r = 0; r < 4; r++) {
            int rr = (w << 4) + (quad << 2) + r;
            n1s[rr * 264 + col] =
                f2b((acc[cb][r] - mean_[r]) * rstd_[r] * gg_[cb] + bb_[cb]);
        }
    }
    WAITLGKM0;
    __builtin_amdgcn_s_barrier();

    // ---- Phase 2: K=256, 8 steps ----
    f32x4 acc2[32];
#pragma unroll
    for (int i = 0; i < 32; i++) acc2[i] = (f32x4){0.f, 0.f, 0.f, 0.f};
    const unsigned short* an1 = n1s + ((w << 4) + l15) * 264 + quad * 8;

#pragma unroll
    for (int s = 0; s < 8; ++s) {
        const char* bufc = Breg + ((s & 1) ? 0 : 32768);
        if (s < 7) {
            char* bufn = Breg + (((s + 1) & 1) ? 0 : 32768);
#pragma unroll
            for (int i = 0; i < 4; i++)
                gl16(wbase + (size_t)(s + 1) * 32768 + ((w * 4 + i) << 10) + lane * 16,
                     bufn + ((w * 4 + i) << 10) + lane * 16);
        }
        bf16x8 a2 = *(const bf16x8*)(an1 + s * 32);
        if (s < 7) { WAITVM(4); } else { WAITVM(0); }
        __builtin_amdgcn_s_barrier();
        const char* Bc = bufc + quad * 8192 + l15 * 16;
#pragma unroll
        for (int cb = 0; cb < 32; cb++) {
            bf16x8 bf = *(const bf16x8*)(Bc + cb * 256);
            acc2[cb] = __builtin_amdgcn_mfma_f32_16x16x32_bf16(a2, bf, acc2[cb], 0, 0, 0);
        }
        WAITLGKM0;
        __builtin_amdgcn_s_barrier();
    }

    // ---- Phase 2 epilogue: + rb, LN(512), residual, store ----
#pragma unroll
    for (int cb = 0; cb < 32; cb++) {
        float bc = b2f(vec[768 + (cb << 4) + l15]);
#pragma unroll
        for (int r = 0; r < 4; r++) acc2[cb][r] += bc;
    }
    float mean2[4], rstd2[4];
#pragma unroll
    for (int r = 0; r < 4; r++) {
        float s = 0.f, q = 0.f;
#pragma unroll
        for (int cb = 0; cb < 32; cb++) { float v = acc2[cb][r]; s += v; q += v * v; }
#pragma unroll
        for (int msk = 1; msk < 16; msk <<= 1) {
            s += __shfl_xor(s, msk, 64);
            q += __shfl_xor(q, msk, 64);
        }
        float mn = s * (1.0f / 512.0f);
        mean2[r] = mn;
        rstd2[r] = rsqrtf(q * (1.0f / 512.0f) - mn * mn + EPS);
    }
    float* rep = (float*)pool;   // [64][516] f32 per row-half (aliases n1s+Breg)
    const int hfw = w >> 2;
#pragma unroll
    for (int hv = 0; hv < 2; ++hv) {
        if (hv) __builtin_amdgcn_s_barrier();   // hv0 reads done before hv1 writes
        if (hfw == hv) {
#pragma unroll
            for (int cb = 0; cb < 32; cb++) {
                int col = (cb << 4) + l15;
                float gg = b2f(vec[1280 + col]), bbv = b2f(vec[1792 + col]);
                int rl = ((w & 3) << 4) + (quad << 2);
#pragma unroll
                for (int r = 0; r < 4; r++)
                    rep[(rl + r) * 516 + col] =
                        (acc2[cb][r] - mean2[r]) * rstd2[r] * gg + bbv;
            }
        }
        WAITLGKM0;
        __builtin_amdgcn_s_barrier();
        int rr = t >> 4, c0 = (t & 15) << 2;
#pragma unroll
        for (int j = 0; j < 8; j++) {
            int col = c0 + (j << 6);
            float4 v0 = *(const float4*)(rep + rr * 516 + col);
            float4 v1 = *(const float4*)(rep + (rr + 32) * 516 + col);
            size_t g0 = (size_t)(row0 + (hv << 6) + rr) * 512 + col;
            size_t g1 = g0 + (size_t)32 * 512;
            float4 xa = *(const float4*)(x1 + g0);
            float4 xb = *(const float4*)(x1 + g1);
            v0.x += xa.x; v0.y += xa.y; v0.z += xa.z; v0.w += xa.w;
            v1.x += xb.x; v1.y += xb.y; v1.z += xb.z; v1.w += xb.w;
            *(float4*)(out + g0) = v0;
            *(float4*)(out + g1) = v1;
        }
        WAITLGKM0;
        __builtin_amdgcn_s_barrier();
    }
}

extern "C" void kernel_launch(void* const* d_in, const int* in_sizes, int n_in,
                              void* d_out, int out_size, void* d_ws, size_t ws_size,
                              hipStream_t stream) {
    const float* x1 = (const float*)d_in[0];
    const float* x2 = (const float*)d_in[1];
    const float* lw = (const float*)d_in[2];
    const float* lb = (const float*)d_in[3];
    const float* g1 = (const float*)d_in[4];
    const float* b1 = (const float*)d_in[5];
    const float* rw = (const float*)d_in[6];
    const float* rb = (const float*)d_in[7];
    const float* ga = (const float*)d_in[8];
    const float* ba = (const float*)d_in[9];
    float* out = (float*)d_out;

    char* ws = (char*)d_ws;
    float*          ctxr  = (float*)(ws);                       // 256 KB
    float2*         stats = (float2*)(ws + 262144);             // 256 KB
    unsigned short* wt1   = (unsigned short*)(ws + 524288);     // 256 KB
    unsigned short* rwb   = (unsigned short*)(ws + 786432);     // 256 KB
    unsigned short* vec   = (unsigned short*)(ws + 1048576);    // 4.5 KB
    unsigned short* w2t   = (unsigned short*)(ws + 1064960);    // 2 MB

    static bool attr_set = false;
    if (!attr_set) {
        hipFuncSetAttribute((const void*)k_fused,
                            hipFuncAttributeMaxDynamicSharedMemorySize, 133120);
        attr_set = true;
    }

    k_params<<<dim3(1289), dim3(256), 0, stream>>>(lw, rw, lb, g1, b1, rb, ga, ba,
                                                   wt1, rwb, vec, ctxr);
    k_stats<<<dim3(8192), dim3(256), 0, stream>>>(x2, stats);
    k_ctx<<<dim3(1024), dim3(256), 0, stream>>>(x2, stats, vec, ctxr);
    k_w2<<<dim3(512), dim3(256), 0, stream>>>(ctxr, rwb, w2t);
    k_fused<<<dim3(256), dim3(512), 133120, stream>>>(x1, wt1, w2t, vec, out);
}